// Round 1
// baseline (1392.454 us; speedup 1.0000x reference)
//
#include <hip/hip_runtime.h>

typedef float  f32x4 __attribute__((ext_vector_type(4)));
typedef short  s16x8 __attribute__((ext_vector_type(8)));
typedef unsigned short u16x8 __attribute__((ext_vector_type(8)));

constexpr int E = 8, H = 2048, IDIM = 4096, T = 8192;
constexpr float ALPHA = 1.702f, LIMIT = 7.0f;

__device__ __forceinline__ unsigned short f2bf(float f) {
    unsigned int u = __builtin_bit_cast(unsigned int, f);
    u += 0x7fffu + ((u >> 16) & 1u);           // round-to-nearest-even
    return (unsigned short)(u >> 16);
}

__device__ __forceinline__ f32x4 mfma16(s16x8 a, s16x8 b, f32x4 c) {
    return __builtin_amdgcn_mfma_f32_16x16x32_bf16(a, b, c, 0, 0, 0);
}

// ---------------------------------------------------------------------------
// Kernel 1: gate+up GEMM fused, per-expert, epilogue = bias + clamp + swiglu,
// writes activated (T x I) bf16 into workspace.
// Tile: 128 tokens x 128 I-cols, BK=32, 4 waves (2x2 of 64x64).
// ---------------------------------------------------------------------------
__global__ __launch_bounds__(256, 2)
void gateup_kernel(const float* __restrict__ x, const int* __restrict__ offs,
                   const float* __restrict__ gate_w, const float* __restrict__ up_w,
                   const float* __restrict__ gate_b, const float* __restrict__ up_b,
                   unsigned short* __restrict__ act)
{
    // k-major fragment layout: As[kb][m][j] holds A[m][kb*8+j]
    __shared__ unsigned short As[4][128][8];
    __shared__ unsigned short Bg[4][128][8];
    __shared__ unsigned short Bu[4][128][8];

    const int tid  = threadIdx.x;
    const int row0 = blockIdx.y * 128;   // token tile start
    const int col0 = blockIdx.x * 128;   // I tile start

    int e = 0;
    while (e < E - 1 && row0 >= offs[e]) ++e;   // expert of this tile (128-aligned groups)

    const float* gw = gate_w + (size_t)e * H * IDIM;
    const float* uw = up_w   + (size_t)e * H * IDIM;

    const int lane = tid & 63;
    const int wave = tid >> 6;
    const int wm   = (wave & 1) * 64;
    const int wn   = (wave >> 1) * 64;
    const int l15  = lane & 15;
    const int quad = lane >> 4;

    // B staging assignment: 8 groups (gate kb0..3, up kb0..3) x 32 threads
    const int n4   = (tid & 31) * 4;
    const int grp  = tid >> 5;
    const int bsel = grp >> 2;     // 0 = gate, 1 = up
    const int bkb  = grp & 3;
    const float* bw = bsel ? uw : gw;
    unsigned short* bdst = bsel ? &Bu[bkb][n4][0] : &Bg[bkb][n4][0];

    const f32x4 fzero = {0.f, 0.f, 0.f, 0.f};
    f32x4 accg[4][4], accu[4][4];
#pragma unroll
    for (int i = 0; i < 4; ++i)
#pragma unroll
        for (int j = 0; j < 4; ++j) { accg[i][j] = fzero; accu[i][j] = fzero; }

    for (int k0 = 0; k0 < H; k0 += 32) {
        // ---- stage A (x tile): 512 octets, 2 per thread, coalesced (4 threads/row)
#pragma unroll
        for (int p = 0; p < 2; ++p) {
            int pair = tid + 256 * p;
            int kb = pair & 3, m = pair >> 2;
            const float* src = x + (size_t)(row0 + m) * H + k0 + kb * 8;
            f32x4 v0 = *(const f32x4*)src;
            f32x4 v1 = *(const f32x4*)(src + 4);
            u16x8 o;
            o[0]=f2bf(v0[0]); o[1]=f2bf(v0[1]); o[2]=f2bf(v0[2]); o[3]=f2bf(v0[3]);
            o[4]=f2bf(v1[0]); o[5]=f2bf(v1[1]); o[6]=f2bf(v1[2]); o[7]=f2bf(v1[3]);
            *(u16x8*)&As[kb][m][0] = o;
        }
        // ---- stage B (weight tile, transpose n-major -> k-major during store)
        {
            const float* src = bw + (size_t)(k0 + bkb * 8) * IDIM + col0 + n4;
            f32x4 v[8];
#pragma unroll
            for (int r = 0; r < 8; ++r) v[r] = *(const f32x4*)(src + (size_t)r * IDIM);
#pragma unroll
            for (int c = 0; c < 4; ++c) {
                u16x8 o;
#pragma unroll
                for (int r = 0; r < 8; ++r) o[r] = f2bf(v[r][c]);
                *(u16x8*)(bdst + c * 8) = o;
            }
        }
        __syncthreads();
        // ---- compute
        s16x8 afr[4], bgf[4], buf[4];
#pragma unroll
        for (int mi = 0; mi < 4; ++mi)
            afr[mi] = *(const s16x8*)&As[quad][wm + mi * 16 + l15][0];
#pragma unroll
        for (int ni = 0; ni < 4; ++ni) {
            bgf[ni] = *(const s16x8*)&Bg[quad][wn + ni * 16 + l15][0];
            buf[ni] = *(const s16x8*)&Bu[quad][wn + ni * 16 + l15][0];
        }
#pragma unroll
        for (int mi = 0; mi < 4; ++mi)
#pragma unroll
            for (int ni = 0; ni < 4; ++ni) {
                accg[mi][ni] = mfma16(afr[mi], bgf[ni], accg[mi][ni]);
                accu[mi][ni] = mfma16(afr[mi], buf[ni], accu[mi][ni]);
            }
        __syncthreads();
    }

    // ---- epilogue: bias + clamp + swiglu, store activated bf16
#pragma unroll
    for (int ni = 0; ni < 4; ++ni) {
        int col = col0 + wn + ni * 16 + l15;
        float gb = gate_b[(size_t)e * IDIM + col];
        float ub = up_b[(size_t)e * IDIM + col];
#pragma unroll
        for (int mi = 0; mi < 4; ++mi) {
            int rowb = row0 + wm + mi * 16 + quad * 4;
#pragma unroll
            for (int r = 0; r < 4; ++r) {
                float g = accg[mi][ni][r] + gb;
                float u = accu[mi][ni][r] + ub;
                g = fminf(g, LIMIT);
                u = fminf(fmaxf(u, -LIMIT), LIMIT);
                float glu = g / (1.0f + __expf(-ALPHA * g));
                float av  = (u + 1.0f) * glu;
                act[(size_t)(rowb + r) * IDIM + col] = f2bf(av);
            }
        }
    }
}

// ---------------------------------------------------------------------------
// Kernel 2: down GEMM: activated(bf16, T x I) @ down_w[e](I x H) + down_b -> out fp32
// Tile: 128 x 128, BK=64, 4 waves.
// ---------------------------------------------------------------------------
__global__ __launch_bounds__(256, 2)
void down_kernel(const unsigned short* __restrict__ act, const int* __restrict__ offs,
                 const float* __restrict__ down_w, const float* __restrict__ down_b,
                 float* __restrict__ out)
{
    __shared__ unsigned short As[8][128][8];
    __shared__ unsigned short Bs[8][128][8];

    const int tid  = threadIdx.x;
    const int row0 = blockIdx.y * 128;   // token tile
    const int col0 = blockIdx.x * 128;   // H tile

    int e = 0;
    while (e < E - 1 && row0 >= offs[e]) ++e;
    const float* dw = down_w + (size_t)e * IDIM * H;

    const int lane = tid & 63;
    const int wave = tid >> 6;
    const int wm   = (wave & 1) * 64;
    const int wn   = (wave >> 1) * 64;
    const int l15  = lane & 15;
    const int quad = lane >> 4;

    const int n4  = (tid & 31) * 4;
    const int bkb = tid >> 5;   // 0..7

    const f32x4 fzero = {0.f, 0.f, 0.f, 0.f};
    f32x4 acc[4][4];
#pragma unroll
    for (int i = 0; i < 4; ++i)
#pragma unroll
        for (int j = 0; j < 4; ++j) acc[i][j] = fzero;

    for (int k0 = 0; k0 < IDIM; k0 += 64) {
        // ---- stage A (activated, already bf16 k-major): direct 16B copies
#pragma unroll
        for (int p = 0; p < 4; ++p) {
            int pair = tid + 256 * p;
            int kb = pair & 7, m = pair >> 3;
            *(u16x8*)&As[kb][m][0] =
                *(const u16x8*)(act + (size_t)(row0 + m) * IDIM + k0 + kb * 8);
        }
        // ---- stage B (down_w tile, transpose during store)
        {
            const float* src = dw + (size_t)(k0 + bkb * 8) * H + col0 + n4;
            f32x4 v[8];
#pragma unroll
            for (int r = 0; r < 8; ++r) v[r] = *(const f32x4*)(src + (size_t)r * H);
#pragma unroll
            for (int c = 0; c < 4; ++c) {
                u16x8 o;
#pragma unroll
                for (int r = 0; r < 8; ++r) o[r] = f2bf(v[r][c]);
                *(u16x8*)&Bs[bkb][n4 + c][0] = o;
            }
        }
        __syncthreads();
        // ---- compute: two K=32 halves per BK=64
        s16x8 a0[4], a1[4], b0[4], b1[4];
#pragma unroll
        for (int mi = 0; mi < 4; ++mi) {
            a0[mi] = *(const s16x8*)&As[quad    ][wm + mi * 16 + l15][0];
            a1[mi] = *(const s16x8*)&As[quad + 4][wm + mi * 16 + l15][0];
        }
#pragma unroll
        for (int ni = 0; ni < 4; ++ni) {
            b0[ni] = *(const s16x8*)&Bs[quad    ][wn + ni * 16 + l15][0];
            b1[ni] = *(const s16x8*)&Bs[quad + 4][wn + ni * 16 + l15][0];
        }
#pragma unroll
        for (int mi = 0; mi < 4; ++mi)
#pragma unroll
            for (int ni = 0; ni < 4; ++ni) {
                acc[mi][ni] = mfma16(a0[mi], b0[ni], acc[mi][ni]);
                acc[mi][ni] = mfma16(a1[mi], b1[ni], acc[mi][ni]);
            }
        __syncthreads();
    }

    // ---- epilogue: + down_b, fp32 store
#pragma unroll
    for (int ni = 0; ni < 4; ++ni) {
        int col = col0 + wn + ni * 16 + l15;
        float db = down_b[(size_t)e * H + col];
#pragma unroll
        for (int mi = 0; mi < 4; ++mi) {
            int rowb = row0 + wm + mi * 16 + quad * 4;
#pragma unroll
            for (int r = 0; r < 4; ++r)
                out[(size_t)(rowb + r) * H + col] = acc[mi][ni][r] + db;
        }
    }
}

extern "C" void kernel_launch(void* const* d_in, const int* in_sizes, int n_in,
                              void* d_out, int out_size, void* d_ws, size_t ws_size,
                              hipStream_t stream) {
    const float* x      = (const float*)d_in[0];
    const int*   offs   = (const int*)d_in[1];
    const float* gate_w = (const float*)d_in[2];
    const float* up_w   = (const float*)d_in[3];
    const float* down_w = (const float*)d_in[4];
    const float* gate_b = (const float*)d_in[5];
    const float* up_b   = (const float*)d_in[6];
    const float* down_b = (const float*)d_in[7];
    float* out = (float*)d_out;
    unsigned short* act = (unsigned short*)d_ws;   // T x I bf16 = 64 MB

    dim3 blk(256);
    dim3 g1(IDIM / 128, T / 128);
    gateup_kernel<<<g1, blk, 0, stream>>>(x, offs, gate_w, up_w, gate_b, up_b, act);
    dim3 g2(H / 128, T / 128);
    down_kernel<<<g2, blk, 0, stream>>>(act, offs, down_w, down_b, out);
}

// Round 2
// 1222.569 us; speedup vs baseline: 1.1390x; 1.1390x over previous
//
#include <hip/hip_runtime.h>

typedef float  f32x4 __attribute__((ext_vector_type(4)));
typedef short  s16x8 __attribute__((ext_vector_type(8)));
typedef unsigned short u16x8 __attribute__((ext_vector_type(8)));
typedef unsigned int   u32x4 __attribute__((ext_vector_type(4)));

constexpr int E = 8, H = 2048, IDIM = 4096, T = 8192;
constexpr float ALPHA = 1.702f, LIMIT = 7.0f;

__device__ __forceinline__ unsigned short f2bf(float f) {
    unsigned int u = __builtin_bit_cast(unsigned int, f);
    u += 0x7fffu + ((u >> 16) & 1u);           // round-to-nearest-even
    return (unsigned short)(u >> 16);
}

// pack two f32 -> packed bf16 (lo = a, hi = b)
__device__ __forceinline__ unsigned int pk_bf16(float a, float b) {
#if __has_builtin(__builtin_amdgcn_cvt_pk_bf16_f32)
    auto v = __builtin_amdgcn_cvt_pk_bf16_f32(a, b);
    return __builtin_bit_cast(unsigned int, v);
#else
    unsigned int ua = __builtin_bit_cast(unsigned int, a);
    unsigned int ub = __builtin_bit_cast(unsigned int, b);
    ua += 0x7fffu + ((ua >> 16) & 1u);
    ub += 0x7fffu + ((ub >> 16) & 1u);
    return __builtin_amdgcn_perm(ub, ua, 0x07060302);  // [ua.b2,ua.b3,ub.b2,ub.b3]
#endif
}

__device__ __forceinline__ f32x4 mfma16(s16x8 a, s16x8 b, f32x4 c) {
    return __builtin_amdgcn_mfma_f32_16x16x32_bf16(a, b, c, 0, 0, 0);
}

// B swizzle: octet column n -> n ^ ((n>>2)&7)  (breaks stride-4-octet write conflicts)
__device__ __forceinline__ int bswz(int n) { return n ^ ((n >> 2) & 7); }

// ---------------------------------------------------------------------------
// Kernel 1: gate+up GEMM fused, epilogue = bias + clamp + swiglu -> act bf16.
// Tile: 128 x 128, BK=32, 4 waves. LDS octet columns XOR-swizzled.
// ---------------------------------------------------------------------------
__global__ __launch_bounds__(256, 2)
void gateup_kernel(const float* __restrict__ x, const int* __restrict__ offs,
                   const float* __restrict__ gate_w, const float* __restrict__ up_w,
                   const float* __restrict__ gate_b, const float* __restrict__ up_b,
                   unsigned short* __restrict__ act)
{
    // A swizzle: col = m ^ (2*kb); B swizzle: col = bswz(n)
    __shared__ __align__(16) unsigned short As[4][128][8];
    __shared__ __align__(16) unsigned short Bg[4][128][8];
    __shared__ __align__(16) unsigned short Bu[4][128][8];

    const int tid  = threadIdx.x;
    const int row0 = blockIdx.y * 128;
    const int col0 = blockIdx.x * 128;

    int e = 0;
    while (e < E - 1 && row0 >= offs[e]) ++e;

    const float* gw = gate_w + (size_t)e * H * IDIM;
    const float* uw = up_w   + (size_t)e * H * IDIM;

    const int lane = tid & 63;
    const int wave = tid >> 6;
    const int wm   = (wave & 1) * 64;
    const int wn   = (wave >> 1) * 64;
    const int l15  = lane & 15;
    const int quad = lane >> 4;

    const int n4   = (tid & 31) * 4;
    const int grp  = tid >> 5;
    const int bsel = grp >> 2;     // 0 = gate, 1 = up
    const int bkb  = grp & 3;
    const float* bw = bsel ? uw : gw;
    unsigned short* brow0 = bsel ? &Bu[bkb][0][0] : &Bg[bkb][0][0];

    const f32x4 fzero = {0.f, 0.f, 0.f, 0.f};
    f32x4 accg[4][4], accu[4][4];
#pragma unroll
    for (int i = 0; i < 4; ++i)
#pragma unroll
        for (int j = 0; j < 4; ++j) { accg[i][j] = fzero; accu[i][j] = fzero; }

    for (int k0 = 0; k0 < H; k0 += 32) {
        // ---- stage A: 512 octets, 2/thread, coalesced (4 threads per row)
#pragma unroll
        for (int p = 0; p < 2; ++p) {
            int pair = tid + 256 * p;
            int kb = pair & 3, m = pair >> 2;
            const float* src = x + (size_t)(row0 + m) * H + k0 + kb * 8;
            f32x4 v0 = *(const f32x4*)src;
            f32x4 v1 = *(const f32x4*)(src + 4);
            u32x4 o = { pk_bf16(v0[0], v0[1]), pk_bf16(v0[2], v0[3]),
                        pk_bf16(v1[0], v1[1]), pk_bf16(v1[2], v1[3]) };
            *(u32x4*)&As[kb][m ^ (2 * kb)][0] = o;
        }
        // ---- stage B: transpose n-major -> k-major, swizzled store
        {
            const float* src = bw + (size_t)(k0 + bkb * 8) * IDIM + col0 + n4;
            f32x4 v[8];
#pragma unroll
            for (int r = 0; r < 8; ++r) v[r] = *(const f32x4*)(src + (size_t)r * IDIM);
#pragma unroll
            for (int c = 0; c < 4; ++c) {
                u32x4 o = { pk_bf16(v[0][c], v[1][c]), pk_bf16(v[2][c], v[3][c]),
                            pk_bf16(v[4][c], v[5][c]), pk_bf16(v[6][c], v[7][c]) };
                *(u32x4*)(brow0 + (size_t)bswz(n4 + c) * 8) = o;
            }
        }
        __syncthreads();
        // ---- compute
        s16x8 afr[4], bgf[4], buf[4];
#pragma unroll
        for (int mi = 0; mi < 4; ++mi) {
            int m = wm + mi * 16 + l15;
            afr[mi] = *(const s16x8*)&As[quad][m ^ (2 * quad)][0];
        }
#pragma unroll
        for (int ni = 0; ni < 4; ++ni) {
            int n = wn + ni * 16 + l15;
            bgf[ni] = *(const s16x8*)&Bg[quad][bswz(n)][0];
            buf[ni] = *(const s16x8*)&Bu[quad][bswz(n)][0];
        }
#pragma unroll
        for (int mi = 0; mi < 4; ++mi)
#pragma unroll
            for (int ni = 0; ni < 4; ++ni) {
                accg[mi][ni] = mfma16(afr[mi], bgf[ni], accg[mi][ni]);
                accu[mi][ni] = mfma16(afr[mi], buf[ni], accu[mi][ni]);
            }
        __syncthreads();
    }

    // ---- epilogue: bias + clamp + swiglu -> act bf16
#pragma unroll
    for (int ni = 0; ni < 4; ++ni) {
        int col = col0 + wn + ni * 16 + l15;
        float gb = gate_b[(size_t)e * IDIM + col];
        float ub = up_b[(size_t)e * IDIM + col];
#pragma unroll
        for (int mi = 0; mi < 4; ++mi) {
            int rowb = row0 + wm + mi * 16 + quad * 4;
#pragma unroll
            for (int r = 0; r < 4; ++r) {
                float g = accg[mi][ni][r] + gb;
                float u = accu[mi][ni][r] + ub;
                g = fminf(g, LIMIT);
                u = fminf(fmaxf(u, -LIMIT), LIMIT);
                float glu = g / (1.0f + __expf(-ALPHA * g));
                float av  = (u + 1.0f) * glu;
                act[(size_t)(rowb + r) * IDIM + col] = f2bf(av);
            }
        }
    }
}

// ---------------------------------------------------------------------------
// Kernel 2: down GEMM: act(bf16) @ down_w + down_b -> out fp32.
// Tile: 128 x 128, BK=64, 4 waves. Swizzled LDS.
// ---------------------------------------------------------------------------
__global__ __launch_bounds__(256, 2)
void down_kernel(const unsigned short* __restrict__ act, const int* __restrict__ offs,
                 const float* __restrict__ down_w, const float* __restrict__ down_b,
                 float* __restrict__ out)
{
    // A swizzle: col = m ^ kb; B swizzle: col = bswz(n)
    __shared__ __align__(16) unsigned short As[8][128][8];
    __shared__ __align__(16) unsigned short Bs[8][128][8];

    const int tid  = threadIdx.x;
    const int row0 = blockIdx.y * 128;
    const int col0 = blockIdx.x * 128;

    int e = 0;
    while (e < E - 1 && row0 >= offs[e]) ++e;
    const float* dw = down_w + (size_t)e * IDIM * H;

    const int lane = tid & 63;
    const int wave = tid >> 6;
    const int wm   = (wave & 1) * 64;
    const int wn   = (wave >> 1) * 64;
    const int l15  = lane & 15;
    const int quad = lane >> 4;

    const int n4  = (tid & 31) * 4;
    const int bkb = tid >> 5;   // 0..7

    const f32x4 fzero = {0.f, 0.f, 0.f, 0.f};
    f32x4 acc[4][4];
#pragma unroll
    for (int i = 0; i < 4; ++i)
#pragma unroll
        for (int j = 0; j < 4; ++j) acc[i][j] = fzero;

    for (int k0 = 0; k0 < IDIM; k0 += 64) {
        // ---- stage A (bf16 k-major already): 16B copies, swizzled dest
#pragma unroll
        for (int p = 0; p < 4; ++p) {
            int pair = tid + 256 * p;
            int kb = pair & 7, m = pair >> 3;
            *(u16x8*)&As[kb][m ^ kb][0] =
                *(const u16x8*)(act + (size_t)(row0 + m) * IDIM + k0 + kb * 8);
        }
        // ---- stage B: transpose + convert, swizzled store
        {
            const float* src = dw + (size_t)(k0 + bkb * 8) * H + col0 + n4;
            f32x4 v[8];
#pragma unroll
            for (int r = 0; r < 8; ++r) v[r] = *(const f32x4*)(src + (size_t)r * H);
#pragma unroll
            for (int c = 0; c < 4; ++c) {
                u32x4 o = { pk_bf16(v[0][c], v[1][c]), pk_bf16(v[2][c], v[3][c]),
                            pk_bf16(v[4][c], v[5][c]), pk_bf16(v[6][c], v[7][c]) };
                *(u32x4*)&Bs[bkb][bswz(n4 + c)][0] = o;
            }
        }
        __syncthreads();
        // ---- compute: two K=32 halves
        s16x8 a0[4], a1[4], b0[4], b1[4];
#pragma unroll
        for (int mi = 0; mi < 4; ++mi) {
            int m = wm + mi * 16 + l15;
            a0[mi] = *(const s16x8*)&As[quad    ][m ^ quad      ][0];
            a1[mi] = *(const s16x8*)&As[quad + 4][m ^ (quad + 4)][0];
        }
#pragma unroll
        for (int ni = 0; ni < 4; ++ni) {
            int n = wn + ni * 16 + l15;
            b0[ni] = *(const s16x8*)&Bs[quad    ][bswz(n)][0];
            b1[ni] = *(const s16x8*)&Bs[quad + 4][bswz(n)][0];
        }
#pragma unroll
        for (int mi = 0; mi < 4; ++mi)
#pragma unroll
            for (int ni = 0; ni < 4; ++ni) {
                acc[mi][ni] = mfma16(a0[mi], b0[ni], acc[mi][ni]);
                acc[mi][ni] = mfma16(a1[mi], b1[ni], acc[mi][ni]);
            }
        __syncthreads();
    }

    // ---- epilogue: + down_b, fp32 store
#pragma unroll
    for (int ni = 0; ni < 4; ++ni) {
        int col = col0 + wn + ni * 16 + l15;
        float db = down_b[(size_t)e * H + col];
#pragma unroll
        for (int mi = 0; mi < 4; ++mi) {
            int rowb = row0 + wm + mi * 16 + quad * 4;
#pragma unroll
            for (int r = 0; r < 4; ++r)
                out[(size_t)(rowb + r) * H + col] = acc[mi][ni][r] + db;
        }
    }
}

extern "C" void kernel_launch(void* const* d_in, const int* in_sizes, int n_in,
                              void* d_out, int out_size, void* d_ws, size_t ws_size,
                              hipStream_t stream) {
    const float* x      = (const float*)d_in[0];
    const int*   offs   = (const int*)d_in[1];
    const float* gate_w = (const float*)d_in[2];
    const float* up_w   = (const float*)d_in[3];
    const float* down_w = (const float*)d_in[4];
    const float* gate_b = (const float*)d_in[5];
    const float* up_b   = (const float*)d_in[6];
    const float* down_b = (const float*)d_in[7];
    float* out = (float*)d_out;
    unsigned short* act = (unsigned short*)d_ws;   // T x I bf16 = 64 MB

    dim3 blk(256);
    dim3 g1(IDIM / 128, T / 128);
    gateup_kernel<<<g1, blk, 0, stream>>>(x, offs, gate_w, up_w, gate_b, up_b, act);
    dim3 g2(H / 128, T / 128);
    down_kernel<<<g2, blk, 0, stream>>>(act, offs, down_w, down_b, out);
}